// Round 24
// baseline (108.816 us; speedup 1.0000x reference)
//
#include <hip/hip_runtime.h>

#define NB 8
#define NN 128
#define ND 64
#define NE 3
#define NH 256
#define NOUT 64

typedef short bf16x8_t __attribute__((ext_vector_type(8)));
typedef float f32x4_t __attribute__((ext_vector_type(4)));
typedef unsigned short ushort_t;

static __device__ __forceinline__ unsigned short f2bf(float f) {
    unsigned u = __float_as_uint(f);
    u += 0x7FFFu + ((u >> 16) & 1u);
    return (unsigned short)(u >> 16);
}
static __device__ __forceinline__ unsigned pk2bf(float a, float b) {
    return (unsigned)f2bf(a) | ((unsigned)f2bf(b) << 16);
}

// A-fragment gen from f32 P,Q: relu(P+Q) -> bf16 pack
static __device__ __forceinline__ bf16x8_t a_genf(float4 p0, float4 p1, float4 q0, float4 q1) {
    union { uint4 u; bf16x8_t v; } r;
    r.u.x = pk2bf(fmaxf(p0.x + q0.x, 0.f), fmaxf(p0.y + q0.y, 0.f));
    r.u.y = pk2bf(fmaxf(p0.z + q0.z, 0.f), fmaxf(p0.w + q0.w, 0.f));
    r.u.z = pk2bf(fmaxf(p1.x + q1.x, 0.f), fmaxf(p1.y + q1.y, 0.f));
    r.u.w = pk2bf(fmaxf(p1.z + q1.z, 0.f), fmaxf(p1.w + q1.w, 0.f));
    return r.v;
}

// ============ Kernel 1: We2p pack (0..47) + P/Q f32 (48..239) ============
// We2p layout (ushorts): [((e*16 + nf)*8 + kk)*512 + lane*8 + jj]
//   = bf16(We2[e][k = kk*32 + (lane>>4)*8 + jj][n = nf*16 + (lane&15)])
#define IT 16
__global__ __launch_bounds__(256) void prep_kernel(
    const float* __restrict__ We2, const float* __restrict__ ns,
    const float* __restrict__ We1, const float* __restrict__ be1,
    ushort_t* __restrict__ We2p,
    float* __restrict__ P, float* __restrict__ Q)
{
    const int t = threadIdx.x;
    const int blk = blockIdx.x;

    if (blk < 48) {             // ---- We2p fragment pack ----
        __shared__ float slab[256][16];
        const int e = blk >> 4, nfg = blk & 15;
        const int n0 = nfg * 16;
#pragma unroll
        for (int it = 0; it < 16; it++) {
            const int k = (t >> 4) + it * 16;
            slab[k][t & 15] = We2[((size_t)e * NH + k) * NH + n0 + (t & 15)];
        }
        __syncthreads();
        ushort_t* dst = We2p + ((size_t)e * 16 + nfg) * 4096;
#pragma unroll
        for (int it = 0; it < 16; it++) {
            const int idx = it * 256 + t;
            const int kk = idx >> 9;
            const int ln = (idx >> 3) & 63;
            const int jj = idx & 7;
            const int k = kk * 32 + (ln >> 4) * 8 + jj;
            dst[idx] = f2bf(slab[k][ln & 15]);
        }
        return;
    }
    // ---- P/Q precompute -> f32 ----
    {
        __shared__ float ns_lds[IT][ND];
        const int blk2 = blk - 48;
        const int itile = blk2 & 7;
        const int e = (blk2 >> 3) % NE;
        const int b = blk2 / 24;
        const int i0 = itile * IT;
        for (int x = t; x < IT * ND; x += 256)
            ns_lds[x / ND][x % ND] = ns[(size_t)(b * NN + i0 + x / ND) * ND + (x % ND)];
        __syncthreads();
        const int h = t;
        float accP[IT], accQ[IT];
        const float bias = be1[e * NH + h];
#pragma unroll
        for (int m = 0; m < IT; m++) { accP[m] = 0.f; accQ[m] = bias; }
        const float* W1 = We1 + (size_t)e * 2 * ND * NH + h;
        for (int d = 0; d < ND; d++) {
            const float w1 = W1[(size_t)d * NH];
            const float w2 = W1[(size_t)(ND + d) * NH];
#pragma unroll
            for (int m = 0; m < IT; m++) {
                accP[m] = fmaf(ns_lds[m][d], w1, accP[m]);
                accQ[m] = fmaf(ns_lds[m][d], w2, accQ[m]);
            }
        }
#pragma unroll
        for (int m = 0; m < IT; m++) {
            const size_t idx = ((size_t)((b * NE + e) * NN) + i0 + m) * NH + h;
            P[idx] = accP[m];
            Q[idx] = accQ[m];
        }
    }
}

// ============ Kernel 2: FUSED edge-pack + gemm (e-loop, full-B LDS) + decoder ============
// block = (b, 4 j's); 1024 thr = 16 waves = 4 j x 4 col-quarters; grid 256 (1 block/CU)
__global__ __launch_bounds__(1024) void fused_kernel(
    const float* __restrict__ ns,
    const float* __restrict__ edges,
    const float* __restrict__ Pf,
    const float* __restrict__ Qf,
    const ushort_t* __restrict__ We2p,
    const float* __restrict__ be2,
    const float* __restrict__ Wd1, const float* __restrict__ bd1,
    const float* __restrict__ Wd2, const float* __restrict__ bd2,
    float* __restrict__ out)
{
    const int b = blockIdx.x >> 5;
    const int jq = blockIdx.x & 31;
    const int j0 = jq * 4;
    const int tid = threadIdx.x;
    const int lane = tid & 63;
    const int wave = tid >> 6;
    const int jj = wave >> 2;      // 0..3: which j
    const int cq = wave & 3;       // 0..3: 64-col quarter
    const int j = j0 + jj;

    __shared__ __align__(16) ushort_t Bl[16 * 8 * 512];   // 128 KB, [nfg][kk][512]
    __shared__ ushort_t lists[4][NN];
    __shared__ int cnts[4][3];
    __shared__ unsigned long long wm[4][2][3];
    __shared__ float aggrL[4][NH];
    __shared__ __align__(16) float xs[4][320];
    __shared__ __align__(16) float o1s[4][NH];

    // ---- inline edge classification for the block's 4 j's ----
    int ecls = -1;
    if (tid < 512) {
        const int ii = tid & 127;
        const float4 ev = *(const float4*)(edges + ((size_t)(b * NN + ii) * NN + j0 + (tid >> 7)) * 4);
        ecls = ev.y > 0.5f ? 0 : (ev.z > 0.5f ? 1 : (ev.w > 0.5f ? 2 : -1));
    }
#pragma unroll
    for (int ee = 0; ee < 3; ee++) {
        unsigned long long m = __ballot(ecls == ee);
        if (lane == 0 && wave < 8) wm[wave >> 1][wave & 1][ee] = m;
    }
    __syncthreads();
    if (tid < 512 && ecls >= 0) {
        const int jl = tid >> 7, w2 = (tid >> 6) & 1, ii = tid & 127;
        const unsigned long long lower = (1ull << lane) - 1ull;
        int pos = __popcll(wm[jl][w2][ecls] & lower);
        if (w2) pos += __popcll(wm[jl][0][ecls]);
        const int c0 = __popcll(wm[jl][0][0]) + __popcll(wm[jl][1][0]);
        const int c1 = __popcll(wm[jl][0][1]) + __popcll(wm[jl][1][1]);
        pos += (ecls > 0 ? c0 : 0) + (ecls > 1 ? c1 : 0);
        lists[jl][pos] = (ushort_t)ii;
    }
    if (tid < 16) {
        const int jl = tid >> 2, ee = tid & 3;
        if (ee < 3) cnts[jl][ee] = __popcll(wm[jl][0][ee]) + __popcll(wm[jl][1][ee]);
    }

    float rsum[4] = {0.f, 0.f, 0.f, 0.f};

    for (int e = 0; e < NE; e++) {
        __syncthreads();   // prev-e readers done (e=0: lists/cnts visible)
        {   // ---- stage full B e-slab: 128 KB L2 -> LDS, coalesced ----
            const ushort_t* Bsrc = We2p + (size_t)e * 65536;
#pragma unroll
            for (int it = 0; it < 8; it++) {
                const int o = it * 8192 + tid * 8;
                *(uint4*)&Bl[o] = *(const uint4*)&Bsrc[o];
            }
        }
        __syncthreads();

        const int ce = cnts[jj][e];
        const int start = (e > 0 ? cnts[jj][0] : 0) + (e > 1 ? cnts[jj][1] : 0);
        const ushort_t* Lj = &lists[jj][start];
        const float* Qj = Qf + (size_t)((b * NE + e) * NN + j) * NH;
        const float* Pb = Pf + (size_t)(b * NE + e) * NN * NH;
        float bb[4];
#pragma unroll
        for (int nf = 0; nf < 4; nf++)
            bb[nf] = be2[e * NH + cq * 64 + nf * 16 + (lane & 15)];

        if (ce > 0) {
            const int F = (ce + 15) >> 4;
            for (int f = 0; f < F; f++) {
                int p = f * 16 + (lane & 15);
                p = p < ce ? p : ce - 1;
                const float* P0 = Pb + (size_t)Lj[p] * NH;

                f32x4_t acc[4];
                const f32x4_t z4 = {0.f, 0.f, 0.f, 0.f};
#pragma unroll
                for (int nf = 0; nf < 4; nf++) acc[nf] = z4;

#pragma unroll 2
                for (int kk = 0; kk < 8; kk++) {
                    const int ko = kk * 32 + (lane >> 4) * 8;
                    const float4 q0 = *(const float4*)(Qj + ko);
                    const float4 q1 = *(const float4*)(Qj + ko + 4);
                    const float4 p0 = *(const float4*)(P0 + ko);
                    const float4 p1 = *(const float4*)(P0 + ko + 4);
                    const bf16x8_t af = a_genf(p0, p1, q0, q1);
#pragma unroll
                    for (int nf = 0; nf < 4; nf++) {
                        const bf16x8_t bfr = *(const bf16x8_t*)(&Bl[((cq * 4 + nf) * 8 + kk) * 512 + lane * 8]);
                        acc[nf] = __builtin_amdgcn_mfma_f32_16x16x32_bf16(af, bfr, acc[nf], 0, 0, 0);
                    }
                }
                // epilogue: bias+relu+row-mask, cross-lane col reduce; accumulate across e
#pragma unroll
                for (int nf = 0; nf < 4; nf++) {
                    float s = 0.f;
#pragma unroll
                    for (int r = 0; r < 4; r++) {
                        const int pos = f * 16 + ((lane >> 4) << 2) + r;
                        if (pos < ce) s += fmaxf(acc[nf][r] + bb[nf], 0.f);
                    }
                    s += __shfl_xor(s, 16, 64);
                    s += __shfl_xor(s, 32, 64);
                    if (lane < 16) rsum[nf] += s;
                }
            }
        }
    }

    // ---- aggr to LDS (unique writer per (jj, col)) ----
    if (lane < 16) {
#pragma unroll
        for (int nf = 0; nf < 4; nf++)
            aggrL[jj][cq * 64 + nf * 16 + lane] = rsum[nf];
    }
    __syncthreads();

    // ---- decoder: xs = [ns(64) | aggr(256)] for 4 j's ----
    for (int x = tid; x < 4 * 320; x += 1024) {
        const int jl = x / 320, k = x % 320;
        xs[jl][k] = k < ND ? ns[(size_t)(b * NN + j0 + jl) * ND + k] : aggrL[jl][k - ND];
    }
    __syncthreads();
    {   // layer 1: 1024 threads = 4 jl x 256 cols
        const int jl = tid >> 8, n = tid & 255;
        float a = bd1[n];
        for (int k4 = 0; k4 < 80; k4++) {
            const float4 xv = *(const float4*)(&xs[jl][k4 * 4]);
            a = fmaf(xv.x, Wd1[(size_t)(k4 * 4 + 0) * NH + n], a);
            a = fmaf(xv.y, Wd1[(size_t)(k4 * 4 + 1) * NH + n], a);
            a = fmaf(xv.z, Wd1[(size_t)(k4 * 4 + 2) * NH + n], a);
            a = fmaf(xv.w, Wd1[(size_t)(k4 * 4 + 3) * NH + n], a);
        }
        o1s[jl][n] = fmaxf(a, 0.f);
    }
    __syncthreads();
    if (tid < 256) {   // layer 2: 4 jl x 64 cols
        const int jl = tid >> 6, col = tid & 63;
        float a = bd2[col];
        for (int h4 = 0; h4 < 64; h4++) {
            const float4 ov = *(const float4*)(&o1s[jl][h4 * 4]);
            a = fmaf(ov.x, Wd2[(size_t)(h4 * 4 + 0) * NOUT + col], a);
            a = fmaf(ov.y, Wd2[(size_t)(h4 * 4 + 1) * NOUT + col], a);
            a = fmaf(ov.z, Wd2[(size_t)(h4 * 4 + 2) * NOUT + col], a);
            a = fmaf(ov.w, Wd2[(size_t)(h4 * 4 + 3) * NOUT + col], a);
        }
        out[(size_t)(b * NN + j0 + jl) * NOUT + col] = fmaxf(a, 0.f);
    }
}

extern "C" void kernel_launch(void* const* d_in, const int* in_sizes, int n_in,
                              void* d_out, int out_size, void* d_ws, size_t ws_size,
                              hipStream_t stream)
{
    const float* ns    = (const float*)d_in[0];
    const float* edges = (const float*)d_in[1];
    const float* We1   = (const float*)d_in[2];
    const float* be1   = (const float*)d_in[3];
    const float* We2   = (const float*)d_in[4];
    const float* be2   = (const float*)d_in[5];
    const float* Wd1   = (const float*)d_in[6];
    const float* bd1   = (const float*)d_in[7];
    const float* Wd2   = (const float*)d_in[8];
    const float* bd2   = (const float*)d_in[9];
    float* outp = (float*)d_out;

    // ws layout (~6.7 MB)
    float* Pf = (float*)d_ws;                               // 786432 f32
    float* Qf = Pf + (size_t)NB * NE * NN * NH;             // 786432 f32
    ushort_t* We2p = (ushort_t*)(Qf + (size_t)NB * NE * NN * NH); // 196608 us

    hipLaunchKernelGGL(prep_kernel, dim3(240), dim3(256), 0, stream,
                       We2, ns, We1, be1, We2p, Pf, Qf);
    hipLaunchKernelGGL(fused_kernel, dim3(256), dim3(1024), 0, stream,
                       ns, edges, Pf, Qf, We2p, be2, Wd1, bd1, Wd2, bd2, outp);
}

// Round 25
// 74.131 us; speedup vs baseline: 1.4679x; 1.4679x over previous
//
#include <hip/hip_runtime.h>

#define NB 8
#define NN 128
#define ND 64
#define NE 3
#define NH 256
#define NOUT 64

typedef short bf16x8_t __attribute__((ext_vector_type(8)));
typedef float f32x4_t __attribute__((ext_vector_type(4)));
typedef unsigned short ushort_t;

static __device__ __forceinline__ unsigned short f2bf(float f) {
    unsigned u = __float_as_uint(f);
    u += 0x7FFFu + ((u >> 16) & 1u);
    return (unsigned short)(u >> 16);
}
static __device__ __forceinline__ unsigned pk2bf(float a, float b) {
    return (unsigned)f2bf(a) | ((unsigned)f2bf(b) << 16);
}

// A-fragment gen from f32 P,Q: relu(P+Q) -> bf16 pack
static __device__ __forceinline__ bf16x8_t a_genf(float4 p0, float4 p1, float4 q0, float4 q1) {
    union { uint4 u; bf16x8_t v; } r;
    r.u.x = pk2bf(fmaxf(p0.x + q0.x, 0.f), fmaxf(p0.y + q0.y, 0.f));
    r.u.y = pk2bf(fmaxf(p0.z + q0.z, 0.f), fmaxf(p0.w + q0.w, 0.f));
    r.u.z = pk2bf(fmaxf(p1.x + q1.x, 0.f), fmaxf(p1.y + q1.y, 0.f));
    r.u.w = pk2bf(fmaxf(p1.z + q1.z, 0.f), fmaxf(p1.w + q1.w, 0.f));
    return r.v;
}

// ============ Kernel 1: We2p pack (0..47) + P/Q f32 (48..239) + edge pack (240..1263) ============
// We2p layout (ushorts): [((e*16 + nf)*8 + kk)*512 + lane*8 + jj]
//   = bf16(We2[e][k = kk*32 + (lane>>4)*8 + jj][n = nf*16 + (lane&15)])
#define IT 16
__global__ __launch_bounds__(256) void prep_kernel(
    const float* __restrict__ We2, const float* __restrict__ ns,
    const float* __restrict__ We1, const float* __restrict__ be1,
    const float* __restrict__ edges,
    ushort_t* __restrict__ We2p,
    float* __restrict__ P, float* __restrict__ Q,
    ushort_t* __restrict__ list_ws, int4* __restrict__ cnts_ws)
{
    const int t = threadIdx.x;
    const int blk = blockIdx.x;

    if (blk < 48) {             // ---- We2p fragment pack ----
        __shared__ float slab[256][16];
        const int e = blk >> 4, nfg = blk & 15;
        const int n0 = nfg * 16;
#pragma unroll
        for (int it = 0; it < 16; it++) {
            const int k = (t >> 4) + it * 16;
            slab[k][t & 15] = We2[((size_t)e * NH + k) * NH + n0 + (t & 15)];
        }
        __syncthreads();
        ushort_t* dst = We2p + ((size_t)e * 16 + nfg) * 4096;
#pragma unroll
        for (int it = 0; it < 16; it++) {
            const int idx = it * 256 + t;
            const int kk = idx >> 9;
            const int ln = (idx >> 3) & 63;
            const int jj = idx & 7;
            const int k = kk * 32 + (ln >> 4) * 8 + jj;
            dst[idx] = f2bf(slab[k][ln & 15]);
        }
        return;
    }
    if (blk < 240) {            // ---- P/Q precompute -> f32 ----
        __shared__ float ns_lds[IT][ND];
        const int blk2 = blk - 48;
        const int itile = blk2 & 7;
        const int e = (blk2 >> 3) % NE;
        const int b = blk2 / 24;
        const int i0 = itile * IT;
        for (int x = t; x < IT * ND; x += 256)
            ns_lds[x / ND][x % ND] = ns[(size_t)(b * NN + i0 + x / ND) * ND + (x % ND)];
        __syncthreads();
        const int h = t;
        float accP[IT], accQ[IT];
        const float bias = be1[e * NH + h];
#pragma unroll
        for (int m = 0; m < IT; m++) { accP[m] = 0.f; accQ[m] = bias; }
        const float* W1 = We1 + (size_t)e * 2 * ND * NH + h;
        for (int d = 0; d < ND; d++) {
            const float w1 = W1[(size_t)d * NH];
            const float w2 = W1[(size_t)(ND + d) * NH];
#pragma unroll
            for (int m = 0; m < IT; m++) {
                accP[m] = fmaf(ns_lds[m][d], w1, accP[m]);
                accQ[m] = fmaf(ns_lds[m][d], w2, accQ[m]);
            }
        }
#pragma unroll
        for (int m = 0; m < IT; m++) {
            const size_t idx = ((size_t)((b * NE + e) * NN) + i0 + m) * NH + h;
            P[idx] = accP[m];
            Q[idx] = accQ[m];
        }
        return;
    }
    // ---- edge pack: per (b,j): bucketed source lists by edge type ----
    {
        __shared__ unsigned long long wm[2][NE];
        const int pb = blk - 240;
        const int b = pb >> 7, j = pb & 127;
        const int lane = t & 63, wave = t >> 6;
        int ecls = -1;
        if (t < 128) {
            const float4 ev = *(const float4*)(edges + ((size_t)(b * NN + t) * NN + j) * 4);
            ecls = ev.y > 0.5f ? 0 : (ev.z > 0.5f ? 1 : (ev.w > 0.5f ? 2 : -1));
#pragma unroll
            for (int ee = 0; ee < NE; ee++) {
                unsigned long long m = __ballot(ecls == ee);
                if (lane == 0) wm[wave][ee] = m;
            }
        }
        __syncthreads();
        const int c0 = __popcll(wm[0][0]) + __popcll(wm[1][0]);
        const int c1 = __popcll(wm[0][1]) + __popcll(wm[1][1]);
        const int c2 = __popcll(wm[0][2]) + __popcll(wm[1][2]);
        if (t < 128 && ecls >= 0) {
            const unsigned long long lower = (1ull << lane) - 1ull;
            int pos = __popcll(wm[wave][ecls] & lower);
            if (wave == 1) pos += __popcll(wm[0][ecls]);
            pos += (ecls > 0 ? c0 : 0) + (ecls > 1 ? c1 : 0);
            list_ws[(size_t)pb * NN + pos] = (ushort_t)t;
        }
        if (t == 0) { int4 cc; cc.x = c0; cc.y = c1; cc.z = c2; cc.w = 0; cnts_ws[pb] = cc; }
    }
}

// ============ Kernel 2: full-B + Q in LDS; grid 384, 512 thr, wave = 1 j x 256 cols ============
__global__ __launch_bounds__(512) void gemm_kernel(
    const float* __restrict__ Pf,
    const float* __restrict__ Qf,
    const ushort_t* __restrict__ We2p,
    const float* __restrict__ be2,
    const ushort_t* __restrict__ list_ws,
    const int4* __restrict__ cnts_ws,
    float* __restrict__ aggr3)
{
    // grid: 384 = b(8) x e(3) x jg(16); 8 waves; wave owns j = jg*8 + wave
    const int blk = blockIdx.x;
    const int jg = blk & 15;
    const int e  = (blk >> 4) % 3;
    const int b  = blk / 48;
    const int tid = threadIdx.x;
    const int lane = tid & 63;
    const int wave = tid >> 6;

    __shared__ __align__(16) ushort_t Bl[16 * 8 * 512];   // 128 KB: [nf][kk][512]
    __shared__ __align__(16) float Ql[8 * NH];            // 8 KB: Q rows for the 8 j's

    {   // ---- one-time stage: B slab (coalesced) + Q rows ----
        const ushort_t* Bsrc = We2p + (size_t)e * 65536;
#pragma unroll
        for (int it = 0; it < 16; it++) {
            const int o = it * 4096 + tid * 8;
            *(uint4*)&Bl[o] = *(const uint4*)&Bsrc[o];
        }
        const float* Qs = Qf + (size_t)((b * NE + e) * NN + jg * 8) * NH;
        *(float4*)(Ql + tid * 4) = *(const float4*)(Qs + tid * 4);
    }

    const int j = jg * 8 + wave;
    const int4 cc = cnts_ws[b * NN + j];
    const int ce = e == 0 ? cc.x : (e == 1 ? cc.y : cc.z);
    const int start = (e > 0 ? cc.x : 0) + (e > 1 ? cc.y : 0);
    const ushort_t* Lj = list_ws + (size_t)(b * NN + j) * NN + start;
    const float* Pb = Pf + (size_t)(b * NE + e) * NN * NH;

    float bb[16];
#pragma unroll
    for (int nf = 0; nf < 16; nf++)
        bb[nf] = be2[e * NH + nf * 16 + (lane & 15)];

    __syncthreads();   // Bl + Ql visible; only barrier
    const float* Qj = Ql + wave * NH;

    float rsum[16];
#pragma unroll
    for (int nf = 0; nf < 16; nf++) rsum[nf] = 0.f;

    if (ce > 0) {
        const int F = (ce + 15) >> 4;
        for (int f = 0; f < F; f++) {
            int p = f * 16 + (lane & 15);
            p = p < ce ? p : ce - 1;
            const float* P0 = Pb + (size_t)Lj[p] * NH;

            f32x4_t acc[16];
            const f32x4_t z4 = {0.f, 0.f, 0.f, 0.f};
#pragma unroll
            for (int nf = 0; nf < 16; nf++) acc[nf] = z4;

#pragma unroll 2
            for (int kk = 0; kk < 8; kk++) {
                const int ko = kk * 32 + (lane >> 4) * 8;
                const float4 q0 = *(const float4*)(Qj + ko);       // LDS
                const float4 q1 = *(const float4*)(Qj + ko + 4);   // LDS
                const float4 p0 = *(const float4*)(P0 + ko);       // L2 gather
                const float4 p1 = *(const float4*)(P0 + ko + 4);
                const bf16x8_t af = a_genf(p0, p1, q0, q1);
#pragma unroll
                for (int nf = 0; nf < 16; nf++) {
                    const bf16x8_t bfr = *(const bf16x8_t*)(&Bl[(nf * 8 + kk) * 512 + lane * 8]);
                    acc[nf] = __builtin_amdgcn_mfma_f32_16x16x32_bf16(af, bfr, acc[nf], 0, 0, 0);
                }
            }
            // epilogue: bias+relu+row-mask, cross-lane col reduce
#pragma unroll
            for (int nf = 0; nf < 16; nf++) {
                float s = 0.f;
#pragma unroll
                for (int r = 0; r < 4; r++) {
                    const int pos = f * 16 + ((lane >> 4) << 2) + r;
                    if (pos < ce) s += fmaxf(acc[nf][r] + bb[nf], 0.f);
                }
                s += __shfl_xor(s, 16, 64);
                s += __shfl_xor(s, 32, 64);
                if (lane < 16) rsum[nf] += s;
            }
        }
    }
    // direct store (unique writer per (b,e,j,col); ce==0 writes zeros)
    if (lane < 16) {
        float* dst = aggr3 + (size_t)((b * NE + e) * NN + j) * NH + lane;
#pragma unroll
        for (int nf = 0; nf < 16; nf++) dst[nf * 16] = rsum[nf];
    }
}

// ============ Kernel 3: decoder, 4 j's per block (256 blocks) ============
__global__ __launch_bounds__(256) void dec_kernel(
    const float* __restrict__ ns,
    const float* __restrict__ aggr3,
    const float* __restrict__ Wd1, const float* __restrict__ bd1,
    const float* __restrict__ Wd2, const float* __restrict__ bd2,
    float* __restrict__ out)
{
    // grid: 256 = b(8) x jq(32); block handles j = jq*4 + 0..3
    const int b = blockIdx.x >> 5;
    const int jq = blockIdx.x & 31;
    const int tid = threadIdx.x;
    __shared__ __align__(16) float xs[4][320];
    __shared__ __align__(16) float o1s[4][NH];

    for (int x = tid; x < 4 * 320; x += 256) {
        const int jj = x / 320, k = x % 320;
        const int j = jq * 4 + jj;
        float v;
        if (k < ND) v = ns[(size_t)(b * NN + j) * ND + k];
        else {
            const int c = k - ND;
            v = aggr3[(size_t)((b * NE + 0) * NN + j) * NH + c]
              + aggr3[(size_t)((b * NE + 1) * NN + j) * NH + c]
              + aggr3[(size_t)((b * NE + 2) * NN + j) * NH + c];
        }
        xs[jj][k] = v;
    }
    __syncthreads();
    {
        const int n = tid;
        float acc[4];
        const float b1 = bd1[n];
#pragma unroll
        for (int jj = 0; jj < 4; jj++) acc[jj] = b1;
        for (int k4 = 0; k4 < 80; k4++) {
            const float w0 = Wd1[(size_t)(k4 * 4 + 0) * NH + n];
            const float w1 = Wd1[(size_t)(k4 * 4 + 1) * NH + n];
            const float w2 = Wd1[(size_t)(k4 * 4 + 2) * NH + n];
            const float w3 = Wd1[(size_t)(k4 * 4 + 3) * NH + n];
#pragma unroll
            for (int jj = 0; jj < 4; jj++) {
                const float4 xv = *(const float4*)(&xs[jj][k4 * 4]);
                acc[jj] = fmaf(xv.x, w0, fmaf(xv.y, w1, fmaf(xv.z, w2, fmaf(xv.w, w3, acc[jj]))));
            }
        }
#pragma unroll
        for (int jj = 0; jj < 4; jj++) o1s[jj][n] = fmaxf(acc[jj], 0.f);
    }
    __syncthreads();
    {
        const int jj = tid >> 6, col = tid & 63;
        float a = bd2[col];
        for (int h4 = 0; h4 < 64; h4++) {
            const float4 ov = *(const float4*)(&o1s[jj][h4 * 4]);
            a = fmaf(ov.x, Wd2[(size_t)(h4 * 4 + 0) * NOUT + col], a);
            a = fmaf(ov.y, Wd2[(size_t)(h4 * 4 + 1) * NOUT + col], a);
            a = fmaf(ov.z, Wd2[(size_t)(h4 * 4 + 2) * NOUT + col], a);
            a = fmaf(ov.w, Wd2[(size_t)(h4 * 4 + 3) * NOUT + col], a);
        }
        const int j = jq * 4 + jj;
        out[(size_t)(b * NN + j) * NOUT + col] = fmaxf(a, 0.f);
    }
}

extern "C" void kernel_launch(void* const* d_in, const int* in_sizes, int n_in,
                              void* d_out, int out_size, void* d_ws, size_t ws_size,
                              hipStream_t stream)
{
    const float* ns    = (const float*)d_in[0];
    const float* edges = (const float*)d_in[1];
    const float* We1   = (const float*)d_in[2];
    const float* be1   = (const float*)d_in[3];
    const float* We2   = (const float*)d_in[4];
    const float* be2   = (const float*)d_in[5];
    const float* Wd1   = (const float*)d_in[6];
    const float* bd1   = (const float*)d_in[7];
    const float* Wd2   = (const float*)d_in[8];
    const float* bd2   = (const float*)d_in[9];
    float* outp = (float*)d_out;

    // ws layout (~10.2 MB)
    float* Pf = (float*)d_ws;                               // 786432 f32
    float* Qf = Pf + (size_t)NB * NE * NN * NH;             // 786432 f32
    ushort_t* We2p = (ushort_t*)(Qf + (size_t)NB * NE * NN * NH); // 196608 us
    ushort_t* list_ws = We2p + (size_t)NE * NH * NH;        // 131072 us
    int4* cnts_ws = (int4*)(list_ws + (size_t)NB * NN * NN);// 1024 int4
    float* aggr3 = (float*)(cnts_ws + NB * NN);             // 786432 f32

    hipLaunchKernelGGL(prep_kernel, dim3(1264), dim3(256), 0, stream,
                       We2, ns, We1, be1, edges, We2p, Pf, Qf, list_ws, cnts_ws);
    hipLaunchKernelGGL(gemm_kernel, dim3(384), dim3(512), 0, stream,
                       Pf, Qf, We2p, be2, list_ws, cnts_ws, aggr3);
    hipLaunchKernelGGL(dec_kernel, dim3(256), dim3(256), 0, stream,
                       ns, aggr3, Wd1, bd1, Wd2, bd2, outp);
}